// Round 1
// baseline (322.044 us; speedup 1.0000x reference)
//
#include <hip/hip_runtime.h>
#include <math.h>

// Bucketed rank/cumsum approach:
//   key = float bits of time (positive floats order monotonically).
//   bucket = key >> 14  -> 131072 buckets covers every positive float.
//   Suffix scans over buckets give (elements above, exp-sum above) per bucket;
//   within-bucket order resolved exactly by brute-force compare (g ~ few hundred).
// Tie-break (key desc, idx asc) matches jax.lax.top_k stability.

#define BSHIFT 14
#define NBUCK (1 << 17)           // 131072; max positive-float key>>14 = 130047
#define SCAN_BLK 1024
#define NPART (NBUCK / SCAN_BLK)  // 128

__global__ void k_hist(const float* __restrict__ yt0, const float* __restrict__ yp0,
                       int n, unsigned* __restrict__ count, float* __restrict__ expsum) {
  int i = blockIdx.x * blockDim.x + threadIdx.x;
  if (i >= n) return;
  unsigned key = __float_as_uint(yt0[2 * i]);
  unsigned b = key >> BSHIFT;
  atomicAdd(&count[b], 1u);
  atomicAdd(&expsum[b], expf(yp0[i]));
}

__global__ void k_scan_reduce(const unsigned* __restrict__ count, const float* __restrict__ expsum,
                              unsigned* __restrict__ cntPart, float* __restrict__ expPart) {
  __shared__ unsigned sc[SCAN_BLK];
  __shared__ float sf[SCAN_BLK];
  int t = threadIdx.x, g = blockIdx.x;
  int b = NBUCK - 1 - (g * SCAN_BLK + t);  // reversed order -> suffix scan
  sc[t] = count[b];
  sf[t] = expsum[b];
  __syncthreads();
  for (int s = SCAN_BLK / 2; s > 0; s >>= 1) {
    if (t < s) { sc[t] += sc[t + s]; sf[t] += sf[t + s]; }
    __syncthreads();
  }
  if (t == 0) { cntPart[g] = sc[0]; expPart[g] = sf[0]; }
}

__global__ void k_scan_parts(unsigned* cntPart, float* expPart) {
  __shared__ unsigned sc[NPART];
  __shared__ float sf[NPART];
  int t = threadIdx.x;
  unsigned myc = cntPart[t];
  float myf = expPart[t];
  sc[t] = myc; sf[t] = myf;
  __syncthreads();
  for (int off = 1; off < NPART; off <<= 1) {
    unsigned c = 0; float f = 0.f;
    if (t >= off) { c = sc[t - off]; f = sf[t - off]; }
    __syncthreads();
    sc[t] += c; sf[t] += f;
    __syncthreads();
  }
  cntPart[t] = sc[t] - myc;  // exclusive prefix of reversed parts
  expPart[t] = sf[t] - myf;
}

__global__ void k_scan_final(const unsigned* __restrict__ count, const float* __restrict__ expsum,
                             const unsigned* __restrict__ cntPart, const float* __restrict__ expPart,
                             unsigned* __restrict__ sfxCnt, float* __restrict__ sfxExp) {
  __shared__ unsigned sc[SCAN_BLK];
  __shared__ float sf[SCAN_BLK];
  int t = threadIdx.x, g = blockIdx.x;
  int b = NBUCK - 1 - (g * SCAN_BLK + t);
  sc[t] = count[b];
  sf[t] = expsum[b];
  __syncthreads();
  for (int off = 1; off < SCAN_BLK; off <<= 1) {
    unsigned c = 0; float f = 0.f;
    if (t >= off) { c = sc[t - off]; f = sf[t - off]; }
    __syncthreads();
    sc[t] += c; sf[t] += f;
    __syncthreads();
  }
  sfxCnt[b] = sc[t] + cntPart[g];  // inclusive suffix: sum over buckets >= b
  sfxExp[b] = sf[t] + expPart[g];
}

__global__ void k_scatter(const float* __restrict__ yt0, const float* __restrict__ yp0, int n,
                          const unsigned* __restrict__ count, const unsigned* __restrict__ sfxCnt,
                          unsigned* __restrict__ cursor,
                          unsigned* __restrict__ skey, unsigned* __restrict__ sidx,
                          float* __restrict__ se) {
  int i = blockIdx.x * blockDim.x + threadIdx.x;
  if (i >= n) return;
  unsigned key = __float_as_uint(yt0[2 * i]);
  unsigned b = key >> BSHIFT;
  unsigned start = sfxCnt[b] - count[b];  // = # elements in strictly-higher buckets
  unsigned pos = start + atomicAdd(&cursor[b], 1u);
  skey[pos] = key;
  sidx[pos] = i;
  se[pos] = expf(yp0[i]);
}

__global__ void k_main(const float* __restrict__ yt0, const float* __restrict__ yp0,
                       const float* __restrict__ yp1, const int* __restrict__ Hj,
                       int n, int m,
                       const unsigned* __restrict__ count, const float* __restrict__ expsum,
                       const unsigned* __restrict__ sfxCnt, const float* __restrict__ sfxExp,
                       const unsigned* __restrict__ skey, const unsigned* __restrict__ sidx,
                       const float* __restrict__ se,
                       float* __restrict__ xh, double* __restrict__ accum) {
  int p = blockIdx.x * blockDim.x + threadIdx.x;
  double contrib = 0.0;
  if (p < n) {
    unsigned key = skey[p];
    unsigned idx = sidx[p];
    float e = se[p];
    unsigned b = key >> BSHIFT;
    unsigned end = sfxCnt[b];
    unsigned start = end - count[b];
    float wsum = 0.f;
    unsigned wcnt = 0;
    for (unsigned q = start; q < end; ++q) {
      unsigned kq = skey[q];
      if (kq > key) { wsum += se[q]; wcnt++; }
      else if (kq == key && sidx[q] < idx) { wsum += se[q]; wcnt++; }
    }
    // denom = exp-sum of all elements strictly before p in descending-time order, + self
    float denom = (sfxExp[b] - expsum[b]) + wsum + e;
    int rank = (int)(start + wcnt);
    float ev = yt0[2 * idx + 1];
    float xb0 = yp0[idx];
    contrib = (double)(ev * (logf(denom) - xb0));  // lossA element
    // scatter y_pred1 to ordinal anchor slots whose sorted position == rank
    int lo = 0, hi = m;
    while (lo < hi) { int mid = (lo + hi) >> 1; if (Hj[mid] < rank) lo = mid + 1; else hi = mid; }
    if (lo < m && Hj[lo] == rank) {
      float xb1 = yp1[idx];
      for (int j = lo; j < m && Hj[j] == rank; ++j) xh[j] = xb1;
    }
  }
  __shared__ double red[256];
  int t = threadIdx.x;
  red[t] = contrib;
  __syncthreads();
  for (int s = 128; s > 0; s >>= 1) {
    if (t < s) red[t] += red[t + s];
    __syncthreads();
  }
  if (t == 0) atomicAdd(accum, red[0]);
}

// cost2 = M(M+1)/2 - sum_j exp(xh_j) * S_j,  S_j = suffix sum of exp(-xh)
__global__ void k_final(const float* __restrict__ xh, int m,
                        const double* __restrict__ accum, const float* __restrict__ log_vars,
                        int n, float* __restrict__ out) {
  __shared__ float sv[1024];
  __shared__ double dred[1024];
  int t = threadIdx.x;
  double acc = 0.0;
  float carry = 0.f;
  int chunks = (m + 1023) / 1024;
  for (int c = chunks - 1; c >= 0; --c) {
    int j = c * 1024 + t;
    float x = (j < m) ? xh[j] : 0.f;
    float v = (j < m) ? expf(-x) : 0.f;
    sv[1023 - t] = v;  // reversed store -> forward scan = suffix scan
    __syncthreads();
    for (int off = 1; off < 1024; off <<= 1) {
      float a = 0.f;
      if (t >= off) a = sv[t - off];
      __syncthreads();
      sv[t] += a;
      __syncthreads();
    }
    float S = sv[1023 - t] + carry;
    if (j < m) acc += (double)(expf(x) * S);
    float total = sv[1023];
    __syncthreads();
    carry += total;
  }
  dred[t] = acc;
  __syncthreads();
  for (int s = 512; s > 0; s >>= 1) {
    if (t < s) dred[t] += dred[t + s];
    __syncthreads();
  }
  if (t == 0) {
    double T = (double)m * (double)(m + 1) * 0.5;
    double cost2 = T - dred[0];
    float lv0 = log_vars[0], lv1 = log_vars[1];
    float prec1 = fminf(expf(-lv1), 1.0f);  // clip(exp(-lv1),0,1)
    double loss = *accum + (double)n * (double)lv0 + (double)prec1 * cost2 + (double)lv1;
    out[0] = (float)loss;
  }
}

extern "C" void kernel_launch(void* const* d_in, const int* in_sizes, int n_in,
                              void* d_out, int out_size, void* d_ws, size_t ws_size,
                              hipStream_t stream) {
  const float* yt0 = (const float*)d_in[0];
  const float* yp0 = (const float*)d_in[2];
  const float* yp1 = (const float*)d_in[3];
  const int*   Hj  = (const int*)d_in[4];
  const float* lv  = (const float*)d_in[5];
  int n = in_sizes[0] / 2;  // y_true0 is [N,2]
  int m = in_sizes[4];

  char* ws = (char*)d_ws;
  size_t off = 0;
  unsigned* count  = (unsigned*)(ws + off); off += (size_t)NBUCK * 4;
  float*    expsum = (float*)(ws + off);    off += (size_t)NBUCK * 4;
  unsigned* cursor = (unsigned*)(ws + off); off += (size_t)NBUCK * 4;
  double*   accum  = (double*)(ws + off);   off += 16;
  size_t zbytes = off;  // everything above must start zeroed
  unsigned* cntPart = (unsigned*)(ws + off); off += (size_t)NPART * 4;
  float*    expPart = (float*)(ws + off);    off += (size_t)NPART * 4;
  unsigned* sfxCnt  = (unsigned*)(ws + off); off += (size_t)NBUCK * 4;
  float*    sfxExp  = (float*)(ws + off);    off += (size_t)NBUCK * 4;
  unsigned* skey    = (unsigned*)(ws + off); off += (size_t)n * 4;
  unsigned* sidx    = (unsigned*)(ws + off); off += (size_t)n * 4;
  float*    se      = (float*)(ws + off);    off += (size_t)n * 4;
  float*    xh      = (float*)(ws + off);    off += (size_t)m * 4;
  // total ~5.8 MB of workspace

  hipMemsetAsync(d_ws, 0, zbytes, stream);

  int blk = 256;
  int g_n = (n + blk - 1) / blk;
  k_hist<<<g_n, blk, 0, stream>>>(yt0, yp0, n, count, expsum);
  k_scan_reduce<<<NPART, SCAN_BLK, 0, stream>>>(count, expsum, cntPart, expPart);
  k_scan_parts<<<1, NPART, 0, stream>>>(cntPart, expPart);
  k_scan_final<<<NPART, SCAN_BLK, 0, stream>>>(count, expsum, cntPart, expPart, sfxCnt, sfxExp);
  k_scatter<<<g_n, blk, 0, stream>>>(yt0, yp0, n, count, sfxCnt, cursor, skey, sidx, se);
  k_main<<<g_n, blk, 0, stream>>>(yt0, yp0, yp1, Hj, n, m, count, expsum, sfxCnt, sfxExp,
                                  skey, sidx, se, xh, accum);
  k_final<<<1, 1024, 0, stream>>>(xh, m, accum, lv, n, (float*)d_out);
}

// Round 3
// 207.684 us; speedup vs baseline: 1.5506x; 1.5506x over previous
//
#include <hip/hip_runtime.h>
#include <math.h>

// Bucketed rank/cumsum (round 3): round-1 structure (BSHIFT=14, proven
// graph-replay-stable) + replicated histograms to cut atomic contention,
// and atomic-free scatter via saved sequence numbers.
//   key = float bits of time (positive floats order monotonically).
//   bucket = key >> 14 -> 2^17 buckets covers every positive float.
//   k_hist: R=8 replicas, r = blockIdx&7 -> ~32-way same-address contention
//     (was 256-way); seq[i] = atomicAdd return = slot within (r,bucket).
//   k_reduce: countTot[b] = sum_r count[r][b]; off[r][b] = exclusive prefix
//     over replicas -> scatter position is fully determined, no cursor atomic.
//   Suffix scans over buckets give (count above, exp-sum above); within-bucket
//   order resolved exactly in k_main by brute-force compare (g ~ 250 max).
// Tie-break (key desc, idx asc) matches jax.lax.top_k stability.

#define BSHIFT 14
#define NBUCK (1 << 17)           // 131072; max positive-float key>>14 = 130047
#define SCAN_BLK 1024
#define NPART (NBUCK / SCAN_BLK)  // 128
#define RMAX 8

__global__ void k_hist(const float* __restrict__ yt0, const float* __restrict__ yp0,
                       int n, int rmask,
                       unsigned* __restrict__ count, float* __restrict__ expsum,
                       unsigned* __restrict__ seq) {
  int i = blockIdx.x * blockDim.x + threadIdx.x;
  if (i >= n) return;
  int r = blockIdx.x & rmask;
  unsigned key = __float_as_uint(yt0[2 * i]);
  unsigned b = key >> BSHIFT;
  seq[i] = atomicAdd(&count[(size_t)r * NBUCK + b], 1u);
  atomicAdd(&expsum[(size_t)r * NBUCK + b], expf(yp0[i]));
}

// Fold replicas: countTot/expTot per bucket + exclusive replica offsets.
__global__ void k_reduce(const unsigned* __restrict__ count, const float* __restrict__ expsum,
                         int nrep,
                         unsigned* __restrict__ countTot, float* __restrict__ expTot,
                         unsigned* __restrict__ offArr) {
  int b = blockIdx.x * blockDim.x + threadIdx.x;
  if (b >= NBUCK) return;
  unsigned tot = 0;
  float ftot = 0.f;
  for (int r = 0; r < nrep; ++r) {
    offArr[(size_t)r * NBUCK + b] = tot;
    tot += count[(size_t)r * NBUCK + b];
    ftot += expsum[(size_t)r * NBUCK + b];
  }
  countTot[b] = tot;
  expTot[b] = ftot;
}

__global__ void k_scan_reduce(const unsigned* __restrict__ count, const float* __restrict__ expsum,
                              unsigned* __restrict__ cntPart, float* __restrict__ expPart) {
  __shared__ unsigned sc[SCAN_BLK];
  __shared__ float sf[SCAN_BLK];
  int t = threadIdx.x, g = blockIdx.x;
  int b = NBUCK - 1 - (g * SCAN_BLK + t);  // reversed order -> suffix scan
  sc[t] = count[b];
  sf[t] = expsum[b];
  __syncthreads();
  for (int s = SCAN_BLK / 2; s > 0; s >>= 1) {
    if (t < s) { sc[t] += sc[t + s]; sf[t] += sf[t + s]; }
    __syncthreads();
  }
  if (t == 0) { cntPart[g] = sc[0]; expPart[g] = sf[0]; }
}

__global__ void k_scan_parts(unsigned* cntPart, float* expPart) {
  __shared__ unsigned sc[NPART];
  __shared__ float sf[NPART];
  int t = threadIdx.x;
  unsigned myc = cntPart[t];
  float myf = expPart[t];
  sc[t] = myc; sf[t] = myf;
  __syncthreads();
  for (int off = 1; off < NPART; off <<= 1) {
    unsigned c = 0; float f = 0.f;
    if (t >= off) { c = sc[t - off]; f = sf[t - off]; }
    __syncthreads();
    sc[t] += c; sf[t] += f;
    __syncthreads();
  }
  cntPart[t] = sc[t] - myc;  // exclusive prefix of reversed parts
  expPart[t] = sf[t] - myf;
}

__global__ void k_scan_final(const unsigned* __restrict__ count, const float* __restrict__ expsum,
                             const unsigned* __restrict__ cntPart, const float* __restrict__ expPart,
                             unsigned* __restrict__ sfxCnt, float* __restrict__ sfxExp) {
  __shared__ unsigned sc[SCAN_BLK];
  __shared__ float sf[SCAN_BLK];
  int t = threadIdx.x, g = blockIdx.x;
  int b = NBUCK - 1 - (g * SCAN_BLK + t);
  sc[t] = count[b];
  sf[t] = expsum[b];
  __syncthreads();
  for (int off = 1; off < SCAN_BLK; off <<= 1) {
    unsigned c = 0; float f = 0.f;
    if (t >= off) { c = sc[t - off]; f = sf[t - off]; }
    __syncthreads();
    sc[t] += c; sf[t] += f;
    __syncthreads();
  }
  sfxCnt[b] = sc[t] + cntPart[g];  // inclusive suffix: sum over buckets >= b
  sfxExp[b] = sf[t] + expPart[g];
}

__global__ void k_scatter(const float* __restrict__ yt0, const float* __restrict__ yp0, int n,
                          int rmask,
                          const unsigned* __restrict__ countTot, const unsigned* __restrict__ sfxCnt,
                          const unsigned* __restrict__ offArr, const unsigned* __restrict__ seq,
                          unsigned* __restrict__ skey, unsigned* __restrict__ sidx,
                          float* __restrict__ se) {
  int i = blockIdx.x * blockDim.x + threadIdx.x;
  if (i >= n) return;
  int r = blockIdx.x & rmask;  // same mapping as k_hist (same grid/block config)
  unsigned key = __float_as_uint(yt0[2 * i]);
  unsigned b = key >> BSHIFT;
  unsigned start = sfxCnt[b] - countTot[b];  // # elements in strictly-higher buckets
  unsigned pos = start + offArr[(size_t)r * NBUCK + b] + seq[i];
  skey[pos] = key;
  sidx[pos] = i;
  se[pos] = expf(yp0[i]);
}

__global__ void k_main(const float* __restrict__ yt0, const float* __restrict__ yp0,
                       const float* __restrict__ yp1, const int* __restrict__ Hj,
                       int n, int m,
                       const unsigned* __restrict__ countTot, const float* __restrict__ expTot,
                       const unsigned* __restrict__ sfxCnt, const float* __restrict__ sfxExp,
                       const unsigned* __restrict__ skey, const unsigned* __restrict__ sidx,
                       const float* __restrict__ se,
                       float* __restrict__ xh, double* __restrict__ accum) {
  int p = blockIdx.x * blockDim.x + threadIdx.x;
  double contrib = 0.0;
  if (p < n) {
    unsigned key = skey[p];
    unsigned idx = sidx[p];
    float e = se[p];
    unsigned b = key >> BSHIFT;
    unsigned end = sfxCnt[b];
    unsigned start = end - countTot[b];
    float wsum = 0.f;
    unsigned wcnt = 0;
    for (unsigned q = start; q < end; ++q) {
      unsigned kq = skey[q];
      if (kq > key) { wsum += se[q]; wcnt++; }
      else if (kq == key && sidx[q] < idx) { wsum += se[q]; wcnt++; }
    }
    // denom = exp-sum of all elements strictly before p in descending-time order, + self
    float denom = (sfxExp[b] - expTot[b]) + wsum + e;
    int rank = (int)(start + wcnt);
    float ev = yt0[2 * idx + 1];
    float xb0 = yp0[idx];
    contrib = (double)(ev * (logf(denom) - xb0));  // lossA element
    // scatter y_pred1 to ordinal anchor slots whose sorted position == rank
    int lo = 0, hi = m;
    while (lo < hi) { int mid = (lo + hi) >> 1; if (Hj[mid] < rank) lo = mid + 1; else hi = mid; }
    if (lo < m && Hj[lo] == rank) {
      float xb1 = yp1[idx];
      for (int j = lo; j < m && Hj[j] == rank; ++j) xh[j] = xb1;
    }
  }
  __shared__ double red[256];
  int t = threadIdx.x;
  red[t] = contrib;
  __syncthreads();
  for (int s = 128; s > 0; s >>= 1) {
    if (t < s) red[t] += red[t + s];
    __syncthreads();
  }
  if (t == 0) atomicAdd(accum, red[0]);
}

// cost2 = M(M+1)/2 - sum_j exp(xh_j) * S_j,  S_j = suffix sum of exp(-xh)
__global__ void k_final(const float* __restrict__ xh, int m,
                        const double* __restrict__ accum, const float* __restrict__ log_vars,
                        int n, float* __restrict__ out) {
  __shared__ float sv[1024];
  __shared__ double dred[1024];
  int t = threadIdx.x;
  double acc = 0.0;
  float carry = 0.f;
  int chunks = (m + 1023) / 1024;
  for (int c = chunks - 1; c >= 0; --c) {
    int j = c * 1024 + t;
    float x = (j < m) ? xh[j] : 0.f;
    float v = (j < m) ? expf(-x) : 0.f;
    sv[1023 - t] = v;  // reversed store -> forward scan = suffix scan
    __syncthreads();
    for (int off = 1; off < 1024; off <<= 1) {
      float a = 0.f;
      if (t >= off) a = sv[t - off];
      __syncthreads();
      sv[t] += a;
      __syncthreads();
    }
    float S = sv[1023 - t] + carry;
    if (j < m) acc += (double)(expf(x) * S);
    float total = sv[1023];
    __syncthreads();
    carry += total;
  }
  dred[t] = acc;
  __syncthreads();
  for (int s = 512; s > 0; s >>= 1) {
    if (t < s) dred[t] += dred[t + s];
    __syncthreads();
  }
  if (t == 0) {
    double T = (double)m * (double)(m + 1) * 0.5;
    double cost2 = T - dred[0];
    float lv0 = log_vars[0], lv1 = log_vars[1];
    float prec1 = fminf(expf(-lv1), 1.0f);  // clip(exp(-lv1),0,1)
    double loss = *accum + (double)n * (double)lv0 + (double)prec1 * cost2 + (double)lv1;
    out[0] = (float)loss;
  }
}

extern "C" void kernel_launch(void* const* d_in, const int* in_sizes, int n_in,
                              void* d_out, int out_size, void* d_ws, size_t ws_size,
                              hipStream_t stream) {
  const float* yt0 = (const float*)d_in[0];
  const float* yp0 = (const float*)d_in[2];
  const float* yp1 = (const float*)d_in[3];
  const int*   Hj  = (const int*)d_in[4];
  const float* lv  = (const float*)d_in[5];
  int n = in_sizes[0] / 2;  // y_true0 is [N,2]
  int m = in_sizes[4];

  // Replica count: 8 if workspace fits (~14 MB), else 1 (~7 MB, = round-1 usage).
  int nrep = RMAX;
  {
    size_t need = (size_t)nrep * NBUCK * 4 * 3   // count, expsum, offArr
                + (size_t)NBUCK * 4 * 4          // countTot, expTot, sfxCnt, sfxExp
                + (size_t)NPART * 4 * 2
                + (size_t)n * 4 * 4              // seq, skey, sidx, se
                + (size_t)m * 4 + 256;
    if (ws_size < need) nrep = 1;
  }
  int rmask = nrep - 1;

  char* ws = (char*)d_ws;
  size_t off = 0;
  unsigned* count  = (unsigned*)(ws + off); off += (size_t)nrep * NBUCK * 4;
  float*    expsum = (float*)(ws + off);    off += (size_t)nrep * NBUCK * 4;
  double*   accum  = (double*)(ws + off);   off += 16;
  size_t zbytes = off;  // everything above must start zeroed
  unsigned* offArr  = (unsigned*)(ws + off); off += (size_t)nrep * NBUCK * 4;
  unsigned* countTot= (unsigned*)(ws + off); off += (size_t)NBUCK * 4;
  float*    expTot  = (float*)(ws + off);    off += (size_t)NBUCK * 4;
  unsigned* cntPart = (unsigned*)(ws + off); off += (size_t)NPART * 4;
  float*    expPart = (float*)(ws + off);    off += (size_t)NPART * 4;
  unsigned* sfxCnt  = (unsigned*)(ws + off); off += (size_t)NBUCK * 4;
  float*    sfxExp  = (float*)(ws + off);    off += (size_t)NBUCK * 4;
  unsigned* seq     = (unsigned*)(ws + off); off += (size_t)n * 4;
  unsigned* skey    = (unsigned*)(ws + off); off += (size_t)n * 4;
  unsigned* sidx    = (unsigned*)(ws + off); off += (size_t)n * 4;
  float*    se      = (float*)(ws + off);    off += (size_t)n * 4;
  float*    xh      = (float*)(ws + off);    off += (size_t)m * 4;

  hipMemsetAsync(d_ws, 0, zbytes, stream);

  int blk = 256;
  int g_n = (n + blk - 1) / blk;
  k_hist<<<g_n, blk, 0, stream>>>(yt0, yp0, n, rmask, count, expsum, seq);
  k_reduce<<<(NBUCK + blk - 1) / blk, blk, 0, stream>>>(count, expsum, nrep,
                                                        countTot, expTot, offArr);
  k_scan_reduce<<<NPART, SCAN_BLK, 0, stream>>>(countTot, expTot, cntPart, expPart);
  k_scan_parts<<<1, NPART, 0, stream>>>(cntPart, expPart);
  k_scan_final<<<NPART, SCAN_BLK, 0, stream>>>(countTot, expTot, cntPart, expPart, sfxCnt, sfxExp);
  k_scatter<<<g_n, blk, 0, stream>>>(yt0, yp0, n, rmask, countTot, sfxCnt, offArr, seq,
                                     skey, sidx, se);
  k_main<<<g_n, blk, 0, stream>>>(yt0, yp0, yp1, Hj, n, m, countTot, expTot, sfxCnt, sfxExp,
                                  skey, sidx, se, xh, accum);
  k_final<<<1, 1024, 0, stream>>>(xh, m, accum, lv, n, (float*)d_out);
}

// Round 5
// 175.645 us; speedup vs baseline: 1.8335x; 1.1824x over previous
//
#include <hip/hip_runtime.h>
#include <math.h>

// Bucketed rank/cumsum (round 5): EXACT round-3 (green, replay-stable) pipeline;
// only change is the k_scatter/k_main data path: interleaved uint2 {key, exp}
// array + 8x unrolled batched loads in k_main's within-bucket scan (MLP fix).
// No LDS staging (round-4's LDS window diverged under graph replay), no new
// kernels, no new sync machinery.
//   key = float bits of time (positive floats order monotonically).
//   bucket = key >> 14 -> 2^17 buckets covers every positive float.
//   k_hist: R=8 replicas -> ~32-way same-address contention; seq[i] = atomicAdd
//     return = slot within (r,bucket). k_reduce folds replicas + replica offsets.
//   Suffix scans over buckets give (count above, exp-sum above); within-bucket
//   order resolved exactly in k_main by brute-force compare (order-invariant).
// Tie-break (key desc, idx asc) matches jax.lax.top_k stability.

#define BSHIFT 14
#define NBUCK (1 << 17)           // 131072; max positive-float key>>14 = 130047
#define SCAN_BLK 1024
#define NPART (NBUCK / SCAN_BLK)  // 128
#define RMAX 8

__global__ void k_hist(const float* __restrict__ yt0, const float* __restrict__ yp0,
                       int n, int rmask,
                       unsigned* __restrict__ count, float* __restrict__ expsum,
                       unsigned* __restrict__ seq) {
  int i = blockIdx.x * blockDim.x + threadIdx.x;
  if (i >= n) return;
  int r = blockIdx.x & rmask;
  unsigned key = __float_as_uint(yt0[2 * i]);
  unsigned b = key >> BSHIFT;
  seq[i] = atomicAdd(&count[(size_t)r * NBUCK + b], 1u);
  atomicAdd(&expsum[(size_t)r * NBUCK + b], expf(yp0[i]));
}

// Fold replicas: countTot/expTot per bucket + exclusive replica offsets.
__global__ void k_reduce(const unsigned* __restrict__ count, const float* __restrict__ expsum,
                         int nrep,
                         unsigned* __restrict__ countTot, float* __restrict__ expTot,
                         unsigned* __restrict__ offArr) {
  int b = blockIdx.x * blockDim.x + threadIdx.x;
  if (b >= NBUCK) return;
  unsigned tot = 0;
  float ftot = 0.f;
  for (int r = 0; r < nrep; ++r) {
    offArr[(size_t)r * NBUCK + b] = tot;
    tot += count[(size_t)r * NBUCK + b];
    ftot += expsum[(size_t)r * NBUCK + b];
  }
  countTot[b] = tot;
  expTot[b] = ftot;
}

__global__ void k_scan_reduce(const unsigned* __restrict__ count, const float* __restrict__ expsum,
                              unsigned* __restrict__ cntPart, float* __restrict__ expPart) {
  __shared__ unsigned sc[SCAN_BLK];
  __shared__ float sf[SCAN_BLK];
  int t = threadIdx.x, g = blockIdx.x;
  int b = NBUCK - 1 - (g * SCAN_BLK + t);  // reversed order -> suffix scan
  sc[t] = count[b];
  sf[t] = expsum[b];
  __syncthreads();
  for (int s = SCAN_BLK / 2; s > 0; s >>= 1) {
    if (t < s) { sc[t] += sc[t + s]; sf[t] += sf[t + s]; }
    __syncthreads();
  }
  if (t == 0) { cntPart[g] = sc[0]; expPart[g] = sf[0]; }
}

__global__ void k_scan_parts(unsigned* cntPart, float* expPart) {
  __shared__ unsigned sc[NPART];
  __shared__ float sf[NPART];
  int t = threadIdx.x;
  unsigned myc = cntPart[t];
  float myf = expPart[t];
  sc[t] = myc; sf[t] = myf;
  __syncthreads();
  for (int off = 1; off < NPART; off <<= 1) {
    unsigned c = 0; float f = 0.f;
    if (t >= off) { c = sc[t - off]; f = sf[t - off]; }
    __syncthreads();
    sc[t] += c; sf[t] += f;
    __syncthreads();
  }
  cntPart[t] = sc[t] - myc;  // exclusive prefix of reversed parts
  expPart[t] = sf[t] - myf;
}

__global__ void k_scan_final(const unsigned* __restrict__ count, const float* __restrict__ expsum,
                             const unsigned* __restrict__ cntPart, const float* __restrict__ expPart,
                             unsigned* __restrict__ sfxCnt, float* __restrict__ sfxExp) {
  __shared__ unsigned sc[SCAN_BLK];
  __shared__ float sf[SCAN_BLK];
  int t = threadIdx.x, g = blockIdx.x;
  int b = NBUCK - 1 - (g * SCAN_BLK + t);
  sc[t] = count[b];
  sf[t] = expsum[b];
  __syncthreads();
  for (int off = 1; off < SCAN_BLK; off <<= 1) {
    unsigned c = 0; float f = 0.f;
    if (t >= off) { c = sc[t - off]; f = sf[t - off]; }
    __syncthreads();
    sc[t] += c; sf[t] += f;
    __syncthreads();
  }
  sfxCnt[b] = sc[t] + cntPart[g];  // inclusive suffix: sum over buckets >= b
  sfxExp[b] = sf[t] + expPart[g];
}

__global__ void k_scatter(const float* __restrict__ yt0, const float* __restrict__ yp0, int n,
                          int rmask,
                          const unsigned* __restrict__ countTot, const unsigned* __restrict__ sfxCnt,
                          const unsigned* __restrict__ offArr, const unsigned* __restrict__ seq,
                          uint2* __restrict__ skey2, unsigned* __restrict__ sidx) {
  int i = blockIdx.x * blockDim.x + threadIdx.x;
  if (i >= n) return;
  int r = blockIdx.x & rmask;  // same mapping as k_hist (same grid/block config)
  unsigned key = __float_as_uint(yt0[2 * i]);
  unsigned b = key >> BSHIFT;
  unsigned start = sfxCnt[b] - countTot[b];  // # elements in strictly-higher buckets
  unsigned pos = start + offArr[(size_t)r * NBUCK + b] + seq[i];
  uint2 v; v.x = key; v.y = __float_as_uint(expf(yp0[i]));
  skey2[pos] = v;
  sidx[pos] = i;
}

__global__ void k_main(const float* __restrict__ yt0, const float* __restrict__ yp0,
                       const float* __restrict__ yp1, const int* __restrict__ Hj,
                       int n, int m,
                       const unsigned* __restrict__ countTot, const float* __restrict__ expTot,
                       const unsigned* __restrict__ sfxCnt, const float* __restrict__ sfxExp,
                       const uint2* __restrict__ skey2, const unsigned* __restrict__ sidx,
                       float* __restrict__ xh, double* __restrict__ accum) {
  int p = blockIdx.x * blockDim.x + threadIdx.x;
  double contrib = 0.0;
  if (p < n) {
    uint2 kv = skey2[p];
    unsigned key = kv.x;
    float e = __uint_as_float(kv.y);
    unsigned idx = sidx[p];
    unsigned b = key >> BSHIFT;
    unsigned end = sfxCnt[b];
    unsigned start = end - countTot[b];
    // defensive clamps: corrupt bounds can never cause runaway loops
    if (end > (unsigned)n) end = (unsigned)n;
    if (start > end) start = end;
    float wsum = 0.f;
    unsigned wcnt = 0;
    unsigned q = start;
    // 8x unrolled batched loads: 8 independent uint2 loads per iteration (MLP);
    // sidx loaded only on exact-key tie (rare).
    while (q + 8 <= end) {
      uint2 v[8];
      #pragma unroll
      for (int k = 0; k < 8; ++k) v[k] = skey2[q + k];
      #pragma unroll
      for (int k = 0; k < 8; ++k) {
        if (v[k].x > key) { wsum += __uint_as_float(v[k].y); wcnt++; }
        else if (v[k].x == key && sidx[q + k] < idx) { wsum += __uint_as_float(v[k].y); wcnt++; }
      }
      q += 8;
    }
    for (; q < end; ++q) {
      uint2 v = skey2[q];
      if (v.x > key) { wsum += __uint_as_float(v.y); wcnt++; }
      else if (v.x == key && sidx[q] < idx) { wsum += __uint_as_float(v.y); wcnt++; }
    }
    // denom = exp-sum of all elements strictly before p in descending-time order, + self
    float denom = (sfxExp[b] - expTot[b]) + wsum + e;
    int rank = (int)(start + wcnt);
    float ev = yt0[2 * idx + 1];
    float xb0 = yp0[idx];
    contrib = (double)(ev * (logf(denom) - xb0));  // lossA element
    // scatter y_pred1 to ordinal anchor slots whose sorted position == rank
    int lo = 0, hi = m;
    while (lo < hi) { int mid = (lo + hi) >> 1; if (Hj[mid] < rank) lo = mid + 1; else hi = mid; }
    if (lo < m && Hj[lo] == rank) {
      float xb1 = yp1[idx];
      for (int j = lo; j < m && Hj[j] == rank; ++j) xh[j] = xb1;
    }
  }
  __shared__ double red[256];
  int t = threadIdx.x;
  red[t] = contrib;
  __syncthreads();
  for (int s = 128; s > 0; s >>= 1) {
    if (t < s) red[t] += red[t + s];
    __syncthreads();
  }
  if (t == 0) atomicAdd(accum, red[0]);
}

// cost2 = M(M+1)/2 - sum_j exp(xh_j) * S_j,  S_j = suffix sum of exp(-xh)
__global__ void k_final(const float* __restrict__ xh, int m,
                        const double* __restrict__ accum, const float* __restrict__ log_vars,
                        int n, float* __restrict__ out) {
  __shared__ float sv[1024];
  __shared__ double dred[1024];
  int t = threadIdx.x;
  double acc = 0.0;
  float carry = 0.f;
  int chunks = (m + 1023) / 1024;
  for (int c = chunks - 1; c >= 0; --c) {
    int j = c * 1024 + t;
    float x = (j < m) ? xh[j] : 0.f;
    float v = (j < m) ? expf(-x) : 0.f;
    sv[1023 - t] = v;  // reversed store -> forward scan = suffix scan
    __syncthreads();
    for (int off = 1; off < 1024; off <<= 1) {
      float a = 0.f;
      if (t >= off) a = sv[t - off];
      __syncthreads();
      sv[t] += a;
      __syncthreads();
    }
    float S = sv[1023 - t] + carry;
    if (j < m) acc += (double)(expf(x) * S);
    float total = sv[1023];
    __syncthreads();
    carry += total;
  }
  dred[t] = acc;
  __syncthreads();
  for (int s = 512; s > 0; s >>= 1) {
    if (t < s) dred[t] += dred[t + s];
    __syncthreads();
  }
  if (t == 0) {
    double T = (double)m * (double)(m + 1) * 0.5;
    double cost2 = T - dred[0];
    float lv0 = log_vars[0], lv1 = log_vars[1];
    float prec1 = fminf(expf(-lv1), 1.0f);  // clip(exp(-lv1),0,1)
    double loss = *accum + (double)n * (double)lv0 + (double)prec1 * cost2 + (double)lv1;
    out[0] = (float)loss;
  }
}

extern "C" void kernel_launch(void* const* d_in, const int* in_sizes, int n_in,
                              void* d_out, int out_size, void* d_ws, size_t ws_size,
                              hipStream_t stream) {
  const float* yt0 = (const float*)d_in[0];
  const float* yp0 = (const float*)d_in[2];
  const float* yp1 = (const float*)d_in[3];
  const int*   Hj  = (const int*)d_in[4];
  const float* lv  = (const float*)d_in[5];
  int n = in_sizes[0] / 2;  // y_true0 is [N,2]
  int m = in_sizes[4];

  // Replica count: 8 if workspace fits (~19 MB), else 1 (~7 MB).
  int nrep = RMAX;
  {
    size_t need = (size_t)nrep * NBUCK * 4 * 3   // count, expsum, offArr
                + (size_t)NBUCK * 4 * 4          // countTot, expTot, sfxCnt, sfxExp
                + (size_t)NPART * 4 * 2
                + (size_t)n * 4 * 4              // seq, skey2 (8B), sidx
                + (size_t)m * 4 + 256;
    if (ws_size < need) nrep = 1;
  }
  int rmask = nrep - 1;

  char* ws = (char*)d_ws;
  size_t off = 0;
  unsigned* count  = (unsigned*)(ws + off); off += (size_t)nrep * NBUCK * 4;
  float*    expsum = (float*)(ws + off);    off += (size_t)nrep * NBUCK * 4;
  double*   accum  = (double*)(ws + off);   off += 16;
  size_t zbytes = off;  // everything above must start zeroed
  unsigned* offArr  = (unsigned*)(ws + off); off += (size_t)nrep * NBUCK * 4;
  unsigned* countTot= (unsigned*)(ws + off); off += (size_t)NBUCK * 4;
  float*    expTot  = (float*)(ws + off);    off += (size_t)NBUCK * 4;
  unsigned* cntPart = (unsigned*)(ws + off); off += (size_t)NPART * 4;
  float*    expPart = (float*)(ws + off);    off += (size_t)NPART * 4;
  unsigned* sfxCnt  = (unsigned*)(ws + off); off += (size_t)NBUCK * 4;
  float*    sfxExp  = (float*)(ws + off);    off += (size_t)NBUCK * 4;
  unsigned* seq     = (unsigned*)(ws + off); off += (size_t)n * 4;
  uint2*    skey2   = (uint2*)(ws + off);    off += (size_t)n * 8;   // 8-aligned
  unsigned* sidx    = (unsigned*)(ws + off); off += (size_t)n * 4;
  float*    xh      = (float*)(ws + off);    off += (size_t)m * 4;

  hipMemsetAsync(d_ws, 0, zbytes, stream);

  int blk = 256;
  int g_n = (n + blk - 1) / blk;
  k_hist<<<g_n, blk, 0, stream>>>(yt0, yp0, n, rmask, count, expsum, seq);
  k_reduce<<<(NBUCK + blk - 1) / blk, blk, 0, stream>>>(count, expsum, nrep,
                                                        countTot, expTot, offArr);
  k_scan_reduce<<<NPART, SCAN_BLK, 0, stream>>>(countTot, expTot, cntPart, expPart);
  k_scan_parts<<<1, NPART, 0, stream>>>(cntPart, expPart);
  k_scan_final<<<NPART, SCAN_BLK, 0, stream>>>(countTot, expTot, cntPart, expPart, sfxCnt, sfxExp);
  k_scatter<<<g_n, blk, 0, stream>>>(yt0, yp0, n, rmask, countTot, sfxCnt, offArr, seq,
                                     skey2, sidx);
  k_main<<<g_n, blk, 0, stream>>>(yt0, yp0, yp1, Hj, n, m, countTot, expTot, sfxCnt, sfxExp,
                                  skey2, sidx, xh, accum);
  k_final<<<1, 1024, 0, stream>>>(xh, m, accum, lv, n, (float*)d_out);
}